// Round 9
// baseline (595.261 us; speedup 1.0000x reference)
//
#include <hip/hip_runtime.h>
#include <hip/hip_bf16.h>

#define N_NODES 50000
#define N_EDGES 1600000
#define IN_F 64
#define E_F 32
#define HID 128
#define OUT_F 4

typedef __attribute__((ext_vector_type(4))) float f32x4;
typedef __attribute__((ext_vector_type(8))) short short8;

__device__ inline short f2bf(float f) {
  union { float f; unsigned u; } v; v.f = f;
  unsigned r = v.u + 0x7FFFu + ((v.u >> 16) & 1u);   // round-to-nearest-even
  return (short)(r >> 16);
}

// -----------------------------------------------------------------------------
// Kernel 1: h16 = bf16(h), row-major (node x 64). 6.4 MB table -> the edge
// kernel gathers THIS instead of a 25.6 MB P table. r8 showed P was swept out
// of L3 ~9x by the 205 MB ef stream (~230 MB refetch); a 6.4 MB table with
// ~2 us re-reference interval stays resident. Also deletes node_pre's GEMM
// and P's 51 MB write+read round trip.
// -----------------------------------------------------------------------------
__global__ __launch_bounds__(256) void cast_h(const float* __restrict__ h,
                                              short* __restrict__ h16) {
  const int i = blockIdx.x * 256 + threadIdx.x;          // 8 floats/thread
  if (i < N_NODES * IN_F / 8) {
    const f32x4 a0 = ((const f32x4*)h)[i * 2];
    const f32x4 a1 = ((const f32x4*)h)[i * 2 + 1];
    short8 pk;
#pragma unroll
    for (int k = 0; k < 4; ++k) pk[k] = f2bf(a0[k]);
#pragma unroll
    for (int k = 0; k < 4; ++k) pk[4 + k] = f2bf(a1[k]);
    ((short8*)h16)[i] = pk;
  }
}

// -----------------------------------------------------------------------------
// Kernel 2: single fused kernel. Per wave: 16-edge tile; full K=160 GEMM
//   hid = [h_u, h_v, e] @ W1 as 5 chained MFMAs per 16-feat slab:
//   chunks k0..31,k32..63 (u) / k64..95,k96..127 (v) / k128..159 (e).
//   A-frags: h_u/h_v gathered from h16 (16 B x2 per endpoint; 4 rowg-lanes of
//   a col cover the node's full 128 B contiguously); e from ef (f32->bf16).
//   B-frags: W1-bf16, PRE-STAGED IN LDS once per block (5 chunks x 8 slabs x
//   64 lanes x 16 B = 40 KB, shared by all 4 waves; lane-consecutive 16 B
//   reads = conflict-free). TPW=25 tiles/wave amortizes the fill.
//   MFMA 16x16x32 layouts (m89-verified): A row=lane&15, k=8*(lane>>4)+i;
//   B col=lane&15, same k; D col=lane&15, row=4*(lane>>4)+reg.
// -----------------------------------------------------------------------------
#define TPW 25   // 16-edge tiles per wave; 1000 blocks x 4 waves x 25 = 100000
__global__ __launch_bounds__(256) void edge_mlp(
    const float* __restrict__ ef, const int* __restrict__ src,
    const int* __restrict__ dst, const float* __restrict__ W1,
    const float* __restrict__ b1, const float* __restrict__ W2,
    const float* __restrict__ b2, const short* __restrict__ h16,
    float* __restrict__ out) {
  __shared__ short8 Bl[5 * 8 * 64];   // 40 KB: B-frag [chunk][slab][lane]

  const int tid  = threadIdx.x;
  const int lane = tid & 63;
  const int wid  = tid >> 6;
  const int col  = lane & 15;     // A-row: edge-in-tile; also B/D col index
  const int rowg = lane >> 4;     // k-group; D row group

  // ---- one-time LDS fill: W1 -> bf16 B-fragments (W1 is L2-hot, 80 KB) ----
  for (int e = tid; e < 5 * 8 * 64; e += 256) {
    const int ln = e & 63, t8 = (e >> 6) & 7, c = e >> 9;
    const int kbase = c * 32 + (ln >> 4) * 8;   // rows: u 0..63, v 64..127, e 128..159
    short8 w;
#pragma unroll
    for (int i = 0; i < 8; ++i)
      w[i] = f2bf(W1[(kbase + i) * HID + t8 * 16 + (ln & 15)]);
    Bl[e] = w;
  }

  // ---- loop-invariant epilogue state ----
  float b1r[8];
  f32x4 w2r[8];
#pragma unroll
  for (int t = 0; t < 8; ++t) {
    b1r[t] = b1[t * 16 + col];
    w2r[t] = ((const f32x4*)W2)[t * 16 + col];   // W2 row (4 floats)
  }
  const f32x4 b2r = *((const f32x4*)b2);
  __syncthreads();                               // Bl ready (only barrier)

  const int g0 = (blockIdx.x * 4 + wid) * TPW;   // wave's first tile id

  for (int tt = 0; tt < TPW; ++tt) {
    const int e0 = (g0 + tt) * 16;

    // ---- idx (16 distinct, coalesced 64 B) + gathers + ef stream ----
    const int sn = src[e0 + col];
    const int dn = dst[e0 + col];
    const short8 au0 = *(const short8*)(h16 + (size_t)sn * IN_F + rowg * 8);
    const short8 au1 = *(const short8*)(h16 + (size_t)sn * IN_F + 32 + rowg * 8);
    const short8 av0 = *(const short8*)(h16 + (size_t)dn * IN_F + rowg * 8);
    const short8 av1 = *(const short8*)(h16 + (size_t)dn * IN_F + 32 + rowg * 8);
    const f32x4* ea = (const f32x4*)(ef + (size_t)(e0 + col) * E_F + rowg * 8);
    const f32x4 a0 = __builtin_nontemporal_load(ea);
    const f32x4 a1 = __builtin_nontemporal_load(ea + 1);
    short8 ae;
#pragma unroll
    for (int i = 0; i < 4; ++i) ae[i] = f2bf(a0[i]);
#pragma unroll
    for (int i = 0; i < 4; ++i) ae[4 + i] = f2bf(a1[i]);

    // ---- 40 MFMAs: 8 slabs x 5 K-chunks (chained C) ----
    f32x4 acc[8];
#pragma unroll
    for (int t = 0; t < 8; ++t) {
      f32x4 c4 = __builtin_amdgcn_mfma_f32_16x16x32_bf16(
          au0, Bl[(0 * 8 + t) * 64 + lane], (f32x4){0.f, 0.f, 0.f, 0.f}, 0, 0, 0);
      c4 = __builtin_amdgcn_mfma_f32_16x16x32_bf16(
          au1, Bl[(1 * 8 + t) * 64 + lane], c4, 0, 0, 0);
      c4 = __builtin_amdgcn_mfma_f32_16x16x32_bf16(
          av0, Bl[(2 * 8 + t) * 64 + lane], c4, 0, 0, 0);
      c4 = __builtin_amdgcn_mfma_f32_16x16x32_bf16(
          av1, Bl[(3 * 8 + t) * 64 + lane], c4, 0, 0, 0);
      acc[t] = __builtin_amdgcn_mfma_f32_16x16x32_bf16(
          ae, Bl[(4 * 8 + t) * 64 + lane], c4, 0, 0, 0);
    }

    // ---- epilogue: bias, relu, project to 4 outs ----
    f32x4 part[4] = {(f32x4){0,0,0,0}, (f32x4){0,0,0,0},
                     (f32x4){0,0,0,0}, (f32x4){0,0,0,0}};
#pragma unroll
    for (int q = 0; q < 4; ++q) {
#pragma unroll
      for (int t = 0; t < 8; ++t) {
        float hid = acc[t][q] + b1r[t];
        hid = fmaxf(hid, 0.f);
#pragma unroll
        for (int o = 0; o < 4; ++o)
          part[q][o] = fmaf(hid, w2r[t][o], part[q][o]);
      }
    }

    // ---- reduce over the 16 col-lanes (xor<16 keeps rowg groups intact) ----
#pragma unroll
    for (int q = 0; q < 4; ++q) {
#pragma unroll
      for (int o = 0; o < 4; ++o) {
        float v = part[q][o];
        v += __shfl_xor(v, 1);
        v += __shfl_xor(v, 2);
        v += __shfl_xor(v, 4);
        v += __shfl_xor(v, 8);
        part[q][o] = v + b2r[o];
      }
    }
    if (col == 0) {
#pragma unroll
      for (int q = 0; q < 4; ++q)
        __builtin_nontemporal_store(part[q],
                                    (f32x4*)out + e0 + rowg * 4 + q);
    }
  }
}

extern "C" void kernel_launch(void* const* d_in, const int* in_sizes, int n_in,
                              void* d_out, int out_size, void* d_ws, size_t ws_size,
                              hipStream_t stream) {
  const float* h   = (const float*)d_in[0];
  const float* ef  = (const float*)d_in[1];
  const int*   src = (const int*)d_in[2];
  const int*   dst = (const int*)d_in[3];
  const float* W1  = (const float*)d_in[4];
  const float* b1  = (const float*)d_in[5];
  const float* W2  = (const float*)d_in[6];
  const float* b2  = (const float*)d_in[7];
  float* out = (float*)d_out;
  short* h16 = (short*)d_ws;     // 50000 * 64 * 2 B = 6.4 MB scratch

  hipLaunchKernelGGL(cast_h, dim3((N_NODES * IN_F / 8 + 255) / 256), dim3(256),
                     0, stream, h, h16);
  // 100000 tiles / (4 waves * TPW=25) = 1000 blocks
  hipLaunchKernelGGL(edge_mlp, dim3(N_EDGES / (16 * 4 * TPW)), dim3(256), 0,
                     stream, ef, src, dst, W1, b1, W2, b2, h16, out);
}